// Round 1
// baseline (1742.280 us; speedup 1.0000x reference)
//
#include <hip/hip_runtime.h>

// Problem constants
constexpr int B_ = 4, E_ = 16, N_ = 1024, D_ = 512;
constexpr int BE = B_ * E_;

#define TILE 64
#define KT 16

// ---------------------------------------------------------------------------
// TN GEMM: C[z] (MxN) = sum_k A[za][k][m] * B[zb][k][n]
// A stored [K][M] row-major, B stored [K][N] row-major (reduce over leading dim).
// za = aMod ? z % aMod : z (aMod=16 for per-expert weights), same for zb.
// ---------------------------------------------------------------------------
__global__ __launch_bounds__(256)
void gemm_tn(const float* __restrict__ A, const float* __restrict__ B,
             float* __restrict__ C, int M, int N, int K,
             int aMod, int bMod)
{
    const int z  = blockIdx.z;
    const int za = aMod ? (z % aMod) : z;
    const int zb = bMod ? (z % bMod) : z;
    const float* Ab = A + (size_t)za * K * M;
    const float* Bb = B + (size_t)zb * K * N;
    float* Cb = C + (size_t)z * M * N;

    __shared__ float As[KT][TILE];
    __shared__ float Bs[KT][TILE];

    const int tx = threadIdx.x, ty = threadIdx.y;
    const int tid = ty * 16 + tx;
    const int m0 = blockIdx.x * TILE;
    const int n0 = blockIdx.y * TILE;

    // staging indices: 256 threads load a 16x64 tile as float4
    const int lr = tid / 16;          // k-row within tile (0..15)
    const int lc = (tid % 16) * 4;    // col within tile (float4)

    float c[4][4] = {};

    for (int k0 = 0; k0 < K; k0 += KT) {
        const float4 a4 = *(const float4*)&Ab[(size_t)(k0 + lr) * M + m0 + lc];
        const float4 b4 = *(const float4*)&Bb[(size_t)(k0 + lr) * N + n0 + lc];
        *(float4*)&As[lr][lc] = a4;
        *(float4*)&Bs[lr][lc] = b4;
        __syncthreads();
#pragma unroll
        for (int kk = 0; kk < KT; ++kk) {
            float a[4], b[4];
#pragma unroll
            for (int i = 0; i < 4; ++i) a[i] = As[kk][ty * 4 + i];
#pragma unroll
            for (int j = 0; j < 4; ++j) b[j] = Bs[kk][tx * 4 + j];
#pragma unroll
            for (int i = 0; i < 4; ++i)
#pragma unroll
                for (int j = 0; j < 4; ++j)
                    c[i][j] += a[i] * b[j];
        }
        __syncthreads();
    }

#pragma unroll
    for (int i = 0; i < 4; ++i) {
        float* cp = &Cb[(size_t)(m0 + ty * 4 + i) * N + n0 + tx * 4];
        *(float4*)cp = make_float4(c[i][0], c[i][1], c[i][2], c[i][3]);
    }
}

// ---------------------------------------------------------------------------
// NN GEMM: C[z] (MxN) = sum_k A[za][m][k] * B[zb][k][n]
// A stored [M][K] row-major, B stored [K][N] row-major.
// ---------------------------------------------------------------------------
__global__ __launch_bounds__(256)
void gemm_nn(const float* __restrict__ A, const float* __restrict__ B,
             float* __restrict__ C, int M, int N, int K,
             int aMod, int bMod)
{
    const int z  = blockIdx.z;
    const int za = aMod ? (z % aMod) : z;
    const int zb = bMod ? (z % bMod) : z;
    const float* Ab = A + (size_t)za * M * K;
    const float* Bb = B + (size_t)zb * K * N;
    float* Cb = C + (size_t)z * M * N;

    __shared__ float As[TILE][KT + 4];   // [m][k], padded row stride (20) keeps
                                         // float4 alignment & spreads banks
    __shared__ float Bs[KT][TILE];

    const int tx = threadIdx.x, ty = threadIdx.y;
    const int tid = ty * 16 + tx;
    const int m0 = blockIdx.x * TILE;
    const int n0 = blockIdx.y * TILE;

    // A tile 64x16: row = tid/4 (0..63), col = (tid%4)*4
    const int ar = tid / 4;
    const int ac = (tid % 4) * 4;
    // B tile 16x64: row = tid/16, col = (tid%16)*4
    const int br = tid / 16;
    const int bc = (tid % 16) * 4;

    float c[4][4] = {};

    for (int k0 = 0; k0 < K; k0 += KT) {
        const float4 a4 = *(const float4*)&Ab[(size_t)(m0 + ar) * K + k0 + ac];
        const float4 b4 = *(const float4*)&Bb[(size_t)(k0 + br) * N + n0 + bc];
        *(float4*)&As[ar][ac] = a4;
        *(float4*)&Bs[br][bc] = b4;
        __syncthreads();
#pragma unroll
        for (int kk = 0; kk < KT; ++kk) {
            float a[4], b[4];
#pragma unroll
            for (int i = 0; i < 4; ++i) a[i] = As[ty * 4 + i][kk];
#pragma unroll
            for (int j = 0; j < 4; ++j) b[j] = Bs[kk][tx * 4 + j];
#pragma unroll
            for (int i = 0; i < 4; ++i)
#pragma unroll
                for (int j = 0; j < 4; ++j)
                    c[i][j] += a[i] * b[j];
        }
        __syncthreads();
    }

#pragma unroll
    for (int i = 0; i < 4; ++i) {
        float* cp = &Cb[(size_t)(m0 + ty * 4 + i) * N + n0 + tx * 4];
        *(float4*)cp = make_float4(c[i][0], c[i][1], c[i][2], c[i][3]);
    }
}

// ---------------------------------------------------------------------------
// Row softmax over D_=512 elements, in place. One 256-thread block per row.
// ---------------------------------------------------------------------------
__global__ __launch_bounds__(256)
void softmax_rows(float* __restrict__ A)
{
    float* p = A + (size_t)blockIdx.x * D_;
    const int t = threadIdx.x;

    float v0 = p[t];
    float v1 = p[t + 256];

    __shared__ float red[256];
    red[t] = fmaxf(v0, v1);
    __syncthreads();
    for (int s = 128; s > 0; s >>= 1) {
        if (t < s) red[t] = fmaxf(red[t], red[t + s]);
        __syncthreads();
    }
    const float m = red[0];
    __syncthreads();

    const float e0 = __expf(v0 - m);
    const float e1 = __expf(v1 - m);
    red[t] = e0 + e1;
    __syncthreads();
    for (int s = 128; s > 0; s >>= 1) {
        if (t < s) red[t] += red[t + s];
        __syncthreads();
    }
    const float inv = 1.0f / red[0];
    p[t]       = e0 * inv;
    p[t + 256] = e1 * inv;
}

// ---------------------------------------------------------------------------
// Orchestration.
//   atten = softmax(W1^T (X^T X) W2)   (per b,e; softmax over last dim)
//   out   = X (W3 atten)
// Buffers: G/M in d_ws (one 64*512*512 fp32 buffer, 67 MB).
//          T and A live in the two halves of d_out until the final GEMM
//          overwrites d_out (final GEMM reads only X and M — no aliasing).
// ---------------------------------------------------------------------------
extern "C" void kernel_launch(void* const* d_in, const int* in_sizes, int n_in,
                              void* d_out, int out_size, void* d_ws, size_t ws_size,
                              hipStream_t stream)
{
    const float* x  = (const float*)d_in[0];
    const float* w1 = (const float*)d_in[1];
    const float* w2 = (const float*)d_in[2];
    const float* w3 = (const float*)d_in[3];
    float* out = (float*)d_out;

    const size_t buf = (size_t)BE * D_ * D_;  // 16,777,216 floats
    float* G  = (float*)d_ws;                 // also reused for M
    float* Tt = out;                          // first half of d_out
    float* A  = out + buf;                    // second half of d_out

    dim3 blk(16, 16);

    // 1) G = X^T X                (TN, M=N=512, K=1024)
    gemm_tn<<<dim3(8, 8, BE), blk, 0, stream>>>(x, x, G, 512, 512, 1024, 0, 0);
    // 2) T = G * W2               (NN, K=512, W2 per-expert)
    gemm_nn<<<dim3(8, 8, BE), blk, 0, stream>>>(G, w2, Tt, 512, 512, 512, 0, E_);
    // 3) A = W1^T * T             (TN, K=512, W1 per-expert)
    gemm_tn<<<dim3(8, 8, BE), blk, 0, stream>>>(w1, Tt, A, 512, 512, 512, E_, 0);
    // 4) softmax over last dim (rows of A are h, length 512 over d)
    softmax_rows<<<BE * D_, 256, 0, stream>>>(A);
    // 5) M = W3 * A_sm            (NN, K=512, W3 per-expert) -> reuse G buffer
    gemm_nn<<<dim3(8, 8, BE), blk, 0, stream>>>(w3, A, G, 512, 512, 512, E_, 0);
    // 6) out = X * M              (NN, M=1024, K=512) — overwrites all of d_out
    gemm_nn<<<dim3(16, 8, BE), blk, 0, stream>>>(x, G, out, 1024, 512, 512, 0, 0);
}

// Round 2
// 746.792 us; speedup vs baseline: 2.3330x; 2.3330x over previous
//
#include <hip/hip_runtime.h>
#include <stdint.h>

typedef unsigned short u16;
typedef __attribute__((ext_vector_type(8))) short bf16x8;
typedef __attribute__((ext_vector_type(4))) float floatx4;
typedef __attribute__((ext_vector_type(4))) u16 u16x4;

constexpr int B_ = 4, E_ = 16, N_ = 1024, D_ = 512;
constexpr int BE = B_ * E_;

__device__ __forceinline__ u16 f2bf(float f) {
    union { float f; uint32_t u; } v; v.f = f;
    return (u16)((v.u + 0x7fffu + ((v.u >> 16) & 1u)) >> 16);
}
__device__ __forceinline__ float bf2f(u16 h) {
    union { uint32_t u; float f; } v; v.u = ((uint32_t)h) << 16;
    return v.f;
}

// async global->LDS, 16B per lane, LDS dest = wave-uniform base + lane*16
#define GLDS(g, l) __builtin_amdgcn_global_load_lds( \
    (const __attribute__((address_space(1))) void*)(g), \
    (__attribute__((address_space(3))) void*)(l), 16, 0, 0)

// ---------------------------------------------------------------------------
// Transpose + split-convert: in [z][R][C] fp32 -> outH/outL [z][C][R] bf16
// grid = (C/32, R/32, z), block = 256
// ---------------------------------------------------------------------------
__global__ __launch_bounds__(256)
void transpose_split(const float* __restrict__ in, u16* __restrict__ outH,
                     u16* __restrict__ outL, int R, int C)
{
    __shared__ float t[32][33];
    const int z = blockIdx.z;
    const float* ib = in + (size_t)z * R * C;
    u16* oh = outH + (size_t)z * R * C;
    u16* ol = outL + (size_t)z * R * C;
    const int r0 = blockIdx.y * 32, c0 = blockIdx.x * 32;
    const int t8 = threadIdx.x & 7, td = threadIdx.x >> 3;  // t8 0..7, td 0..31

    float4 v = *(const float4*)&ib[(size_t)(r0 + td) * C + c0 + t8 * 4];
    t[td][t8 * 4 + 0] = v.x;
    t[td][t8 * 4 + 1] = v.y;
    t[td][t8 * 4 + 2] = v.z;
    t[td][t8 * 4 + 3] = v.w;
    __syncthreads();

    // out row c = c0+td, cols r0 + t8*4 .. +3 ; value = in[r][c] = t[r_local][td]
    u16x4 ph, pl;
    float w0 = t[t8 * 4 + 0][td], w1 = t[t8 * 4 + 1][td];
    float w2 = t[t8 * 4 + 2][td], w3 = t[t8 * 4 + 3][td];
    ph.x = f2bf(w0); pl.x = f2bf(w0 - bf2f(ph.x));
    ph.y = f2bf(w1); pl.y = f2bf(w1 - bf2f(ph.y));
    ph.z = f2bf(w2); pl.z = f2bf(w2 - bf2f(ph.z));
    ph.w = f2bf(w3); pl.w = f2bf(w3 - bf2f(ph.w));
    const size_t o = (size_t)(c0 + td) * R + r0 + t8 * 4;
    *(u16x4*)&oh[o] = ph;
    *(u16x4*)&ol[o] = pl;
}

// ---------------------------------------------------------------------------
// Split-bf16 GEMM (3 MFMA: hh + hl + lh): C[z][m][n] = sum_k A[m][k]*B[n][k]
// A,B hi/lo bf16 arrays, k-contiguous. Out: hi/lo bf16 pair OR fp32.
// 128x128 tile, 256 threads (4 waves), BK=32, 16x16x32 bf16 MFMA.
// ---------------------------------------------------------------------------
__global__ __launch_bounds__(256)
void gemm_split3(const u16* __restrict__ Ah, const u16* __restrict__ Al,
                 int aMod, long aStride,
                 const u16* __restrict__ Bh, const u16* __restrict__ Bl,
                 int bMod, long bStride,
                 u16* __restrict__ Ch, u16* __restrict__ Cl,
                 float* __restrict__ Cf,
                 int M, int N, int K, int f32out)
{
    const int z = blockIdx.z;
    const long za = aMod ? (z % aMod) : z;
    const long zb = bMod ? (z % bMod) : z;
    const u16* pAh = Ah + za * aStride;
    const u16* pAl = Al + za * aStride;
    const u16* pBh = Bh + zb * bStride;
    const u16* pBl = Bl + zb * bStride;

    __shared__ __attribute__((aligned(16))) u16 sAh[128 * 32];
    __shared__ __attribute__((aligned(16))) u16 sAl[128 * 32];
    __shared__ __attribute__((aligned(16))) u16 sBh[128 * 32];
    __shared__ __attribute__((aligned(16))) u16 sBl[128 * 32];

    const int tid = threadIdx.x;
    const int wv = tid >> 6, ln = tid & 63;
    const int m0 = blockIdx.x * 128, n0 = blockIdx.y * 128;

    // staging: lane covers (row = half*64 + wv*16 + ln/4, k = (ln&3)*8)
    const int srow = wv * 16 + (ln >> 2);
    const int skcol = (ln & 3) * 8;
    const int lds0 = (wv * 16) * 32;        // elements
    const int lds1 = (64 + wv * 16) * 32;

    const int quad = ln >> 4, m16 = ln & 15;
    const int wm = wv >> 1, wn = wv & 1;

    floatx4 acc[4][4];
#pragma unroll
    for (int i = 0; i < 4; ++i)
#pragma unroll
        for (int j = 0; j < 4; ++j) acc[i][j] = (floatx4){0.f, 0.f, 0.f, 0.f};

    for (int k0 = 0; k0 < K; k0 += 32) {
        const long ka = k0 + skcol;
        GLDS(pAh + (long)(m0 + srow) * K + ka,      sAh + lds0);
        GLDS(pAh + (long)(m0 + 64 + srow) * K + ka, sAh + lds1);
        GLDS(pAl + (long)(m0 + srow) * K + ka,      sAl + lds0);
        GLDS(pAl + (long)(m0 + 64 + srow) * K + ka, sAl + lds1);
        GLDS(pBh + (long)(n0 + srow) * K + ka,      sBh + lds0);
        GLDS(pBh + (long)(n0 + 64 + srow) * K + ka, sBh + lds1);
        GLDS(pBl + (long)(n0 + srow) * K + ka,      sBl + lds0);
        GLDS(pBl + (long)(n0 + 64 + srow) * K + ka, sBl + lds1);
        __syncthreads();

        bf16x8 ah[4], al[4], bh[4], bl[4];
#pragma unroll
        for (int i = 0; i < 4; ++i) {
            const int off = (wm * 64 + i * 16 + m16) * 32 + quad * 8;
            ah[i] = *(const bf16x8*)&sAh[off];
            al[i] = *(const bf16x8*)&sAl[off];
        }
#pragma unroll
        for (int j = 0; j < 4; ++j) {
            const int off = (wn * 64 + j * 16 + m16) * 32 + quad * 8;
            bh[j] = *(const bf16x8*)&sBh[off];
            bl[j] = *(const bf16x8*)&sBl[off];
        }
#pragma unroll
        for (int i = 0; i < 4; ++i)
#pragma unroll
            for (int j = 0; j < 4; ++j) {
                acc[i][j] = __builtin_amdgcn_mfma_f32_16x16x32_bf16(ah[i], bh[j], acc[i][j], 0, 0, 0);
                acc[i][j] = __builtin_amdgcn_mfma_f32_16x16x32_bf16(ah[i], bl[j], acc[i][j], 0, 0, 0);
                acc[i][j] = __builtin_amdgcn_mfma_f32_16x16x32_bf16(al[i], bh[j], acc[i][j], 0, 0, 0);
            }
        __syncthreads();
    }

    // epilogue: C/D layout col=lane&15, row=quad*4+reg
    const long cbase = (long)z * M * N;
#pragma unroll
    for (int i = 0; i < 4; ++i)
#pragma unroll
        for (int j = 0; j < 4; ++j) {
            const int col = n0 + wn * 64 + j * 16 + m16;
#pragma unroll
            for (int r = 0; r < 4; ++r) {
                const int row = m0 + wm * 64 + i * 16 + quad * 4 + r;
                const long idx = cbase + (long)row * N + col;
                const float v = acc[i][j][r];
                if (f32out) {
                    Cf[idx] = v;
                } else {
                    const u16 h = f2bf(v);
                    Ch[idx] = h;
                    Cl[idx] = f2bf(v - bf2f(h));
                }
            }
        }
}

// ---------------------------------------------------------------------------
// Plain bf16 GEMM, one operand staged on-the-fly from fp32 (hi only).
// OTFA=1: A = Qf (fp32 otf), B = Pb (bf16). OTFA=0: A = Pb, B = Qf.
// ---------------------------------------------------------------------------
template<int OTFA, int F32OUT>
__global__ __launch_bounds__(256)
void gemm_plain(const float* __restrict__ Qf, int qMod, long qStride,
                const u16* __restrict__ Pb, int pMod, long pStride,
                u16* __restrict__ Cb, float* __restrict__ Cf,
                int M, int N, int K)
{
    const int z = blockIdx.z;
    const float* pQ = Qf + (long)(qMod ? z % qMod : z) * qStride;
    const u16*  pP = Pb + (long)(pMod ? z % pMod : z) * pStride;

    __shared__ __attribute__((aligned(16))) u16 sA[128 * 32];
    __shared__ __attribute__((aligned(16))) u16 sB[128 * 32];

    const int tid = threadIdx.x;
    const int wv = tid >> 6, ln = tid & 63;
    const int m0 = blockIdx.x * 128, n0 = blockIdx.y * 128;

    u16* sBF = OTFA ? sB : sA;   // bf16-side LDS tile
    u16* sQ  = OTFA ? sA : sB;   // otf-fp32-side LDS tile
    const int bfRow0 = OTFA ? n0 : m0;
    const int qRow0  = OTFA ? m0 : n0;

    const int srow = wv * 16 + (ln >> 2);
    const int skcol = (ln & 3) * 8;
    const int lds0 = (wv * 16) * 32;
    const int lds1 = (64 + wv * 16) * 32;

    const int frow = tid >> 3;        // 0..31
    const int fk4 = (tid & 7) * 4;    // float4 col

    const int quad = ln >> 4, m16 = ln & 15;
    const int wm = wv >> 1, wn = wv & 1;

    floatx4 acc[4][4];
#pragma unroll
    for (int i = 0; i < 4; ++i)
#pragma unroll
        for (int j = 0; j < 4; ++j) acc[i][j] = (floatx4){0.f, 0.f, 0.f, 0.f};

    for (int k0 = 0; k0 < K; k0 += 32) {
        GLDS(pP + (long)(bfRow0 + srow) * K + k0 + skcol,      sBF + lds0);
        GLDS(pP + (long)(bfRow0 + 64 + srow) * K + k0 + skcol, sBF + lds1);
#pragma unroll
        for (int r4 = 0; r4 < 4; ++r4) {
            const int row = r4 * 32 + frow;
            const float4 v = *(const float4*)&pQ[(long)(qRow0 + row) * K + k0 + fk4];
            u16x4 pk;
            pk.x = f2bf(v.x); pk.y = f2bf(v.y);
            pk.z = f2bf(v.z); pk.w = f2bf(v.w);
            *(u16x4*)&sQ[row * 32 + fk4] = pk;
        }
        __syncthreads();

        bf16x8 af[4], bg[4];
#pragma unroll
        for (int i = 0; i < 4; ++i)
            af[i] = *(const bf16x8*)&sA[(wm * 64 + i * 16 + m16) * 32 + quad * 8];
#pragma unroll
        for (int j = 0; j < 4; ++j)
            bg[j] = *(const bf16x8*)&sB[(wn * 64 + j * 16 + m16) * 32 + quad * 8];
#pragma unroll
        for (int i = 0; i < 4; ++i)
#pragma unroll
            for (int j = 0; j < 4; ++j)
                acc[i][j] = __builtin_amdgcn_mfma_f32_16x16x32_bf16(af[i], bg[j], acc[i][j], 0, 0, 0);
        __syncthreads();
    }

    const long cbase = (long)z * M * N;
#pragma unroll
    for (int i = 0; i < 4; ++i)
#pragma unroll
        for (int j = 0; j < 4; ++j) {
            const int col = n0 + wn * 64 + j * 16 + m16;
#pragma unroll
            for (int r = 0; r < 4; ++r) {
                const int row = m0 + wm * 64 + i * 16 + quad * 4 + r;
                const long idx = cbase + (long)row * N + col;
                if (F32OUT) Cf[idx] = acc[i][j][r];
                else        Cb[idx] = f2bf(acc[i][j][r]);
            }
        }
}

// ---------------------------------------------------------------------------
// Column softmax: AT fp32 [z][512][512], normalize over row index c per col g.
// Out PT bf16 same layout. grid = z*4, block = 128 (each thread one g-column).
// ---------------------------------------------------------------------------
__global__ __launch_bounds__(128)
void softmax_col(const float* __restrict__ AT, u16* __restrict__ PT)
{
    const int z = blockIdx.x >> 2, gq = blockIdx.x & 3;
    const long base = (long)z * 512 * 512 + gq * 128 + threadIdx.x;
    const float* a = AT + base;
    u16* p = PT + base;

    float m = -1e30f, l = 0.f;
    for (int c = 0; c < 512; ++c) {
        const float v = a[(long)c * 512];
        const float mn = fmaxf(m, v);
        l = l * __expf(m - mn) + __expf(v - mn);
        m = mn;
    }
    const float inv = 1.0f / l;
    for (int c = 0; c < 512; ++c) {
        const float v = a[(long)c * 512];
        p[(long)c * 512] = f2bf(__expf(v - m) * inv);
    }
}

// ---------------------------------------------------------------------------
// Orchestration.  atten = softmax(W1^T (X^T X) W2), out = X (W3 atten).
// Logit chain in split-bf16 (err ~2^-17); post-softmax in plain bf16.
// Buffer schedule (proven budget: ws 64 MiB + d_out 128 MiB as scratch):
//   C1: X -> XhT(O[0:64)), XlT(O[64:128))
//   S1: Gh(ws[0:32)), Gl(ws[32:64)) = XT*XT^T          (K=1024, split3)
//   C2a: W2 -> W2T h/l (O[64:80))        [XlT dead]
//   S2: Uh(O[0:32)), Ul(O[32:64)) = W2T*G^T            [XhT dead]
//   C2b: W1 -> W1T h/l (ws[0:16))        [G dead]
//   S3: AT fp32 (O[64:128)) = U*W1T^T                  [W2T dead]
//   S4: PT bf16 (ws[0:32)) = colsoftmax(AT)            [W1T dead]
//   S5: MT bf16 (ws[32:64)) = PT*W3^T (W3 otf)
//   S6: out fp32 (d_out) = X*MT^T (X otf)              [reads only x, MT]
// ---------------------------------------------------------------------------
extern "C" void kernel_launch(void* const* d_in, const int* in_sizes, int n_in,
                              void* d_out, int out_size, void* d_ws, size_t ws_size,
                              hipStream_t stream)
{
    const float* x  = (const float*)d_in[0];
    const float* w1 = (const float*)d_in[1];
    const float* w2 = (const float*)d_in[2];
    const float* w3 = (const float*)d_in[3];

    char* O = (char*)d_out;
    char* W = (char*)d_ws;
    const size_t MB = 1ull << 20;

    u16* XhT  = (u16*)O;
    u16* XlT  = (u16*)(O + 64 * MB);
    u16* Gh   = (u16*)W;
    u16* Gl   = (u16*)(W + 32 * MB);
    u16* W2Th = (u16*)(O + 64 * MB);
    u16* W2Tl = (u16*)(O + 72 * MB);
    u16* Uh   = (u16*)O;
    u16* Ul   = (u16*)(O + 32 * MB);
    u16* W1Th = (u16*)W;
    u16* W1Tl = (u16*)(W + 8 * MB);
    float* AT = (float*)(O + 64 * MB);
    u16* PT   = (u16*)W;
    u16* MT   = (u16*)(W + 32 * MB);
    float* out = (float*)d_out;

    const long sXT = (long)512 * 1024;
    const long sSq = (long)512 * 512;

    // C1: X [z][1024][512] -> XhT/XlT [z][512][1024]
    transpose_split<<<dim3(16, 32, BE), 256, 0, stream>>>(x, XhT, XlT, 1024, 512);
    // S1: G = XT * XT^T (split3, K=1024)
    gemm_split3<<<dim3(4, 4, BE), 256, 0, stream>>>(
        XhT, XlT, 0, sXT, XhT, XlT, 0, sXT,
        Gh, Gl, nullptr, 512, 512, 1024, 0);
    // C2a: W2 -> W2T
    transpose_split<<<dim3(16, 16, E_), 256, 0, stream>>>(w2, W2Th, W2Tl, 512, 512);
    // S2: U = W2T * G^T  (G symmetric)
    gemm_split3<<<dim3(4, 4, BE), 256, 0, stream>>>(
        W2Th, W2Tl, E_, sSq, Gh, Gl, 0, sSq,
        Uh, Ul, nullptr, 512, 512, 512, 0);
    // C2b: W1 -> W1T
    transpose_split<<<dim3(16, 16, E_), 256, 0, stream>>>(w1, W1Th, W1Tl, 512, 512);
    // S3: AT = U * W1T^T  -> fp32 logits, transposed ([c][g])
    gemm_split3<<<dim3(4, 4, BE), 256, 0, stream>>>(
        Uh, Ul, 0, sSq, W1Th, W1Tl, E_, sSq,
        nullptr, nullptr, AT, 512, 512, 512, 1);
    // S4: softmax over c (down the columns of AT)
    softmax_col<<<dim3(BE * 4), 128, 0, stream>>>(AT, PT);
    // S5: MT = PT * W3^T  (W3 fp32 on-the-fly as B)
    gemm_plain<0, 0><<<dim3(4, 4, BE), 256, 0, stream>>>(
        w3, E_, sSq, PT, 0, sSq, MT, nullptr, 512, 512, 512);
    // S6: out = X * MT^T  (X fp32 on-the-fly as A)
    gemm_plain<1, 1><<<dim3(8, 4, BE), 256, 0, stream>>>(
        x, 0, (long)N_ * D_, MT, 0, sSq, nullptr, out, 1024, 512, 512);
}